// Round 5
// baseline (362.717 us; speedup 1.0000x reference)
//
#include <hip/hip_runtime.h>

typedef __bf16 bf16x8 __attribute__((ext_vector_type(8)));
typedef __bf16 bf16x4 __attribute__((ext_vector_type(4)));
typedef float  f32x4  __attribute__((ext_vector_type(4)));

#define BK 64

__device__ __forceinline__ void g2l16(const void* g, void* l) {
    __builtin_amdgcn_global_load_lds((const __attribute__((address_space(1))) void*)g,
                                     (__attribute__((address_space(3))) void*)l, 16, 0, 0);
}

// ---------------------------------------------------------------------------
// proj: q/k/v = xb @ Wb^T + b (all bf16 in), z selects W/bias/output path.
// g2l staging + XOR swizzle; full-line LDS epilogue. (unchanged — off top-5)
__global__ __launch_bounds__(256)
void gemm_proj(const __bf16* __restrict__ A, const __bf16* __restrict__ Wb,
               __bf16* __restrict__ qkv, const float* __restrict__ bpack)
{
    __shared__ __align__(16) __bf16 smem[128 * 128];   // 32768 B
    __bf16* As = smem;
    __bf16* Bs = smem + 128 * BK;

    const int tid  = threadIdx.x;
    const int w    = tid >> 6;
    const int lane = tid & 63;
    const int quad = lane >> 4;
    const int l16  = lane & 15;
    const int wm   = w & 1;
    const int wn   = w >> 1;

    const int m0 = blockIdx.x * 128;
    const int n0 = blockIdx.y * 128;
    const int z  = blockIdx.z;

    const __bf16* Bb   = Wb + (size_t)z * 131072;
    const float*  bias = bpack + z * 256;

    const int srow = (w << 3) + (lane >> 3);
    const int scol = ((lane & 7) ^ (lane >> 3)) << 3;
    char* ldsA = (char*)As + (size_t)w * 1024;
    char* ldsB = (char*)Bs + (size_t)w * 1024;

    const __bf16* Ag = A  + (size_t)(m0 + srow) * 256 + scol;
    const __bf16* Bg = Bb + (size_t)(n0 + srow) * 256 + scol;

    f32x4 acc[4][4] = {};

    for (int k0 = 0; k0 < 256; k0 += BK) {
        __syncthreads();
        #pragma unroll
        for (int c = 0; c < 4; c++)
            g2l16(Ag + (size_t)(c * 32) * 256 + k0, ldsA + c * 4096);
        #pragma unroll
        for (int c = 0; c < 4; c++)
            g2l16(Bg + (size_t)(c * 32) * 256 + k0, ldsB + c * 4096);
        __syncthreads();

        #pragma unroll
        for (int kk = 0; kk < BK; kk += 32) {
            const int ub = kk >> 3;
            bf16x8 a[4], b[4];
            #pragma unroll
            for (int mt = 0; mt < 4; mt++) {
                const int row = wm * 64 + mt * 16 + l16;
                const int cp  = ((quad + ub) ^ (row & 7)) << 3;
                a[mt] = *(const bf16x8*)&As[row * BK + cp];
            }
            #pragma unroll
            for (int nt = 0; nt < 4; nt++) {
                const int row = wn * 64 + nt * 16 + l16;
                const int cp  = ((quad + ub) ^ (row & 7)) << 3;
                b[nt] = *(const bf16x8*)&Bs[row * BK + cp];
            }
            #pragma unroll
            for (int mt = 0; mt < 4; mt++)
                #pragma unroll
                for (int nt = 0; nt < 4; nt++)
                    acc[mt][nt] = __builtin_amdgcn_mfma_f32_16x16x32_bf16(
                        a[mt], b[nt], acc[mt][nt], 0, 0, 0);
        }
    }

    __syncthreads();
    if (z < 2) {
        #pragma unroll
        for (int mt = 0; mt < 4; mt++) {
            const int rl = wm * 64 + mt * 16 + quad * 4;
            #pragma unroll
            for (int nt = 0; nt < 4; nt++) {
                const int cl = wn * 64 + nt * 16 + l16;
                const float bn = bias[n0 + cl];
                #pragma unroll
                for (int r = 0; r < 4; r++) {
                    const int row = rl + r;
                    smem[row * 128 + ((((cl >> 3) ^ (row & 7)) << 3) | (cl & 7))] =
                        (__bf16)(acc[mt][nt][r] + bn);
                }
            }
        }
        __syncthreads();
        __bf16* C = qkv + (size_t)z * 8388608;
        #pragma unroll
        for (int i = 0; i < 8; i++) {
            const int c   = tid + i * 256;
            const int row = c >> 4, u = c & 15;
            *(bf16x8*)&C[(size_t)(m0 + row) * 256 + n0 + u * 8] =
                *(const bf16x8*)&smem[row * 128 + ((u ^ (row & 7)) << 3)];
        }
    } else {
        #pragma unroll
        for (int mt = 0; mt < 4; mt++) {
            const int ml = wm * 64 + mt * 16 + quad * 4;
            #pragma unroll
            for (int nt = 0; nt < 4; nt++) {
                const int dl = wn * 64 + nt * 16 + l16;
                const float bn = bias[n0 + dl];
                bf16x4 pk;
                #pragma unroll
                for (int r = 0; r < 4; r++) pk[r] = (__bf16)(acc[mt][nt][r] + bn);
                *(bf16x4*)&smem[dl * 128 + ((((ml >> 3) ^ (dl & 7)) << 3) | (ml & 7))] = pk;
            }
        }
        __syncthreads();
        __bf16* C = qkv + 2 * 8388608;
        const int bidx = m0 >> 10, mbase = m0 & 1023;
        #pragma unroll
        for (int i = 0; i < 8; i++) {
            const int c  = tid + i * 256;
            const int dl = c >> 4, u = c & 15;
            *(bf16x8*)&C[(size_t)bidx * 262144 + (size_t)(n0 + dl) * 1024 + mbase + u * 8] =
                *(const bf16x8*)&smem[dl * 128 + ((u ^ (dl & 7)) << 3)];
        }
    }
}

// ---------------------------------------------------------------------------
// logits: E[b] = exp(q[b] @ k[b]^T). R5: barrier-free direct-fragment K-loop.
// Each lane's MFMA fragment is a contiguous 16B global slice
// (A[row + l16][kk + quad*8 ..+8]) -> load bf16x8 straight from global; no
// LDS staging, no __syncthreads in the loop. Fragment reuse: sibling waves
// L1-hit; cross-block reuse L2-hit (per-batch q+k = 1MB, XCD-L2-resident
// under the XCD-sequential swizzle). LDS (32KB) only for the full-line
// store epilogue -> occupancy VGPR-bound, waves run unsynchronized (TLP
// latency hiding, which barriers were defeating).
__global__ __launch_bounds__(256)
void gemm_logits(const __bf16* __restrict__ Q, const __bf16* __restrict__ Km,
                 __bf16* __restrict__ E)
{
    __shared__ __align__(16) __bf16 smem[128 * 128];   // epilogue tile only

    const int tid  = threadIdx.x;
    const int w    = tid >> 6;
    const int lane = tid & 63;
    const int quad = lane >> 4;
    const int l16  = lane & 15;
    const int wm   = w & 1;
    const int wn   = w >> 1;

    const int id = blockIdx.x;
    const int x  = id & 7, s = id >> 3;
    const int z  = x + ((s >> 6) << 3);
    const int t_ = s & 63;
    const int m0 = (t_ & 7) * 128;
    const int n0 = (t_ >> 3) * 128;

    const __bf16* Qa = Q  + (size_t)z * 262144
                     + (size_t)(m0 + wm * 64 + l16) * 256 + quad * 8;
    const __bf16* Ka = Km + (size_t)z * 262144
                     + (size_t)(n0 + wn * 64 + l16) * 256 + quad * 8;

    f32x4 acc[4][4] = {};

    #pragma unroll 2
    for (int k = 0; k < 256; k += 32) {
        bf16x8 a[4], b[4];
        #pragma unroll
        for (int mt = 0; mt < 4; mt++)
            a[mt] = *(const bf16x8*)(Qa + mt * (16 * 256) + k);
        #pragma unroll
        for (int nt = 0; nt < 4; nt++)
            b[nt] = *(const bf16x8*)(Ka + nt * (16 * 256) + k);
        #pragma unroll
        for (int mt = 0; mt < 4; mt++)
            #pragma unroll
            for (int nt = 0; nt < 4; nt++)
                acc[mt][nt] = __builtin_amdgcn_mfma_f32_16x16x32_bf16(
                    a[mt], b[nt], acc[mt][nt], 0, 0, 0);
    }

    // epilogue: exp -> swizzled LDS tile -> full-line bf16x8 streaming stores
    #pragma unroll
    for (int mt = 0; mt < 4; mt++) {
        const int rl = wm * 64 + mt * 16 + quad * 4;
        #pragma unroll
        for (int nt = 0; nt < 4; nt++) {
            const int cl = wn * 64 + nt * 16 + l16;
            #pragma unroll
            for (int r = 0; r < 4; r++) {
                const int row = rl + r;
                smem[row * 128 + ((((cl >> 3) ^ (row & 7)) << 3) | (cl & 7))] =
                    (__bf16)__expf(acc[mt][nt][r]);
            }
        }
    }
    __syncthreads();
    __bf16* C = E + (size_t)z * 1048576;
    #pragma unroll
    for (int i = 0; i < 8; i++) {
        const int c   = tid + i * 256;
        const int row = c >> 4, u = c & 15;
        *(bf16x8*)&C[(size_t)(m0 + row) * 1024 + n0 + u * 8] =
            *(const bf16x8*)&smem[row * 128 + ((u ^ (row & 7)) << 3)];
    }
}

// ---------------------------------------------------------------------------
// sum_rcp: rcpS[n,m] = 1 / sum_b E[b,n,m], bf16 out (2 MB). Read-only over E.
__global__ __launch_bounds__(256)
void sum_rcp(const __bf16* __restrict__ E, __bf16* __restrict__ rcpS)
{
    const size_t p = (size_t)blockIdx.x * 256 + threadIdx.x;
    const bf16x8* E8 = (const bf16x8*)E;
    float s[8] = {0.f, 0.f, 0.f, 0.f, 0.f, 0.f, 0.f, 0.f};
    #pragma unroll
    for (int b = 0; b < 32; b++) {
        const bf16x8 e = E8[(size_t)b * 131072 + p];
        #pragma unroll
        for (int j = 0; j < 8; j++) s[j] += (float)e[j];
    }
    bf16x8 o;
    #pragma unroll
    for (int j = 0; j < 8; j++) o[j] = (__bf16)__builtin_amdgcn_rcpf(s[j]);
    ((bf16x8*)rcpS)[p] = o;
}

// ---------------------------------------------------------------------------
// pv: out[z] = (E[z] .* rcpS) @ vT[z]^T. R5: barrier-free direct-fragment
// K-loop, ZERO LDS. Normalization done in registers between load and MFMA.
// R4's dbuf regressed (50.5us, occ 21%): 16 MFMAs can't cover ~200-900cy
// load latency, and 48KB LDS cut co-residency. Here waves are independent
// (no barriers), occupancy is VGPR-bound, and E/vT/rcpS reuse is served by
// L1 (sibling waves) + XCD L2 (neighbor blocks, 2MB rcpS is L2-hot).
// 128x64 tiles, grid 1024, XCD-sequential swizzle.
__global__ __launch_bounds__(256)
void gemm_pv(const __bf16* __restrict__ E, const __bf16* __restrict__ rcpS,
             const __bf16* __restrict__ vT, float* __restrict__ out)
{
    const int tid  = threadIdx.x;
    const int w    = tid >> 6;
    const int lane = tid & 63;
    const int quad = lane >> 4;
    const int l16  = lane & 15;
    const int wm   = w & 1;        // 64-row half
    const int wn   = w >> 1;       // 32-col half

    const int id = blockIdx.x;
    const int x  = id & 7, s = id >> 3;        // s: 0..127
    const int z  = x + ((s >> 5) << 3);        // 4 batches per XCD, sequential
    const int t_ = s & 31;
    const int m0 = (t_ & 7) * 128;             // n-row tile
    const int n0 = (t_ >> 3) * 64;             // d-col tile

    const int arow = m0 + wm * 64 + l16;       // E/rcpS row (n index)
    const __bf16* Ea = E    + (size_t)z * 1048576 + (size_t)arow * 1024 + quad * 8;
    const __bf16* Ra = rcpS +                       (size_t)arow * 1024 + quad * 8;
    const __bf16* Va = vT   + (size_t)z * 262144
                     + (size_t)(n0 + wn * 32 + l16) * 1024 + quad * 8;
    float* Ob = out + (size_t)z * 262144;

    f32x4 acc[4][2] = {};

    #pragma unroll 2
    for (int k = 0; k < 1024; k += 32) {
        bf16x8 a[4], b[2];
        #pragma unroll
        for (int mt = 0; mt < 4; mt++) {
            const bf16x8 e  = *(const bf16x8*)(Ea + mt * (16 * 1024) + k);
            const bf16x8 rs = *(const bf16x8*)(Ra + mt * (16 * 1024) + k);
            #pragma unroll
            for (int j = 0; j < 8; j++)
                a[mt][j] = (__bf16)((float)e[j] * (float)rs[j]);
        }
        #pragma unroll
        for (int nt = 0; nt < 2; nt++)
            b[nt] = *(const bf16x8*)(Va + nt * (16 * 1024) + k);
        #pragma unroll
        for (int mt = 0; mt < 4; mt++)
            #pragma unroll
            for (int nt = 0; nt < 2; nt++)
                acc[mt][nt] = __builtin_amdgcn_mfma_f32_16x16x32_bf16(
                    a[mt], b[nt], acc[mt][nt], 0, 0, 0);
    }

    // fp32 direct stores: 16 lanes x 4B = full 64B lines.
    #pragma unroll
    for (int mt = 0; mt < 4; mt++) {
        const int mb = m0 + wm * 64 + mt * 16 + quad * 4;
        #pragma unroll
        for (int nt = 0; nt < 2; nt++) {
            const int n = n0 + wn * 32 + nt * 16 + l16;
            #pragma unroll
            for (int r = 0; r < 4; r++)
                Ob[(size_t)(mb + r) * 256 + n] = acc[mt][nt][r];
        }
    }
}

// ---------------------------------------------------------------------------
// One launch: x -> bf16, Wq/Wk/Wv -> bf16, pack 3 fp32 biases.
__global__ __launch_bounds__(256)
void cvt_all(const float* __restrict__ x,
             const float* __restrict__ Wq, const float* __restrict__ Wk,
             const float* __restrict__ Wv,
             const float* __restrict__ bq, const float* __restrict__ bk,
             const float* __restrict__ bv,
             __bf16* __restrict__ xb, __bf16* __restrict__ Wqb,
             float* __restrict__ bpack)
{
    const int i = blockIdx.x * 256 + threadIdx.x;
    if (i < 1073152) {
        const float* s; __bf16* d; int off;
        if (i < 1048576)      { s = x;  d = xb;            off = i; }
        else if (i < 1056768) { s = Wq; d = Wqb;           off = i - 1048576; }
        else if (i < 1064960) { s = Wk; d = Wqb + 131072;  off = i - 1056768; }
        else                  { s = Wv; d = Wqb + 262144;  off = i - 1064960; }
        const float4* s4 = (const float4*)s;
        const float4 f0 = s4[off * 2], f1 = s4[off * 2 + 1];
        bf16x8 o;
        o[0] = (__bf16)f0.x; o[1] = (__bf16)f0.y; o[2] = (__bf16)f0.z; o[3] = (__bf16)f0.w;
        o[4] = (__bf16)f1.x; o[5] = (__bf16)f1.y; o[6] = (__bf16)f1.z; o[7] = (__bf16)f1.w;
        ((bf16x8*)d)[off] = o;
    } else if (i < 1073344) {
        const int j = i - 1073152;
        const int sel = j >> 6, jj = j & 63;
        const float* s = sel == 0 ? bq : (sel == 1 ? bk : bv);
        ((float4*)bpack)[j] = ((const float4*)s)[jj];
    }
}

extern "C" void kernel_launch(void* const* d_in, const int* in_sizes, int n_in,
                              void* d_out, int out_size, void* d_ws, size_t ws_size,
                              hipStream_t stream)
{
    const float* x  = (const float*)d_in[0];
    const float* Wq = (const float*)d_in[1];
    const float* bq = (const float*)d_in[2];
    const float* Wk = (const float*)d_in[3];
    const float* bk = (const float*)d_in[4];
    const float* Wv = (const float*)d_in[5];
    const float* bv = (const float*)d_in[6];
    float* out = (float*)d_out;

    // Workspace layout (bytes):
    //   [0,2M)     rcpS bf16 (1024x1024)
    //   [2M,18M)   xb  bf16 (32768x256)
    //   [18M,34M)  q   bf16 \
    //   [34M,50M)  k   bf16  } stride 8388608 elems
    //   [50M,66M)  vT  bf16 (32,256,1024) /
    //   [66M,130M) E   bf16 (32,1024,1024)
    //   [130M,..)  Wqb bf16 (3 x 65536 elems at 131072-elem stride) + bpack
    char* ws = (char*)d_ws;
    __bf16* rcpS = (__bf16*)ws;
    __bf16* xb   = (__bf16*)(ws + (2u  << 20));
    __bf16* qkv  = (__bf16*)(ws + (18u << 20));
    __bf16* E    = (__bf16*)(ws + (66u << 20));
    __bf16* Wqb  = (__bf16*)(ws + (130u << 20));
    float*  bpack = (float*)(ws + (130u << 20) + (1u << 20));

    // 1) converts + bias pack
    cvt_all<<<4194, 256, 0, stream>>>(x, Wq, Wk, Wv, bq, bk, bv, xb, Wqb, bpack);

    // 2) q/k/v projections
    gemm_proj<<<dim3(256, 2, 3), 256, 0, stream>>>(xb, Wqb, qkv, bpack);

    // 3) E[b] = exp(q[b] @ k[b]^T), barrier-free direct-fragment loop
    gemm_logits<<<2048, 256, 0, stream>>>(qkv, qkv + 8388608, E);

    // 4) rcpS[n,m] = 1/sum_b E[b,n,m]  (read-only pass; no E write-back)
    sum_rcp<<<512, 256, 0, stream>>>(E, rcpS);

    // 5) out[b] = (E[b] .* rcpS) @ vT[b]^T, barrier-free, zero-LDS
    gemm_pv<<<1024, 256, 0, stream>>>(E, rcpS, qkv + 2 * 8388608, out);
}

// Round 6
// 188.913 us; speedup vs baseline: 1.9200x; 1.9200x over previous
//
#include <hip/hip_runtime.h>

typedef __bf16 bf16x8 __attribute__((ext_vector_type(8)));
typedef __bf16 bf16x4 __attribute__((ext_vector_type(4)));
typedef float  f32x4  __attribute__((ext_vector_type(4)));

#define BK 64

__device__ __forceinline__ void g2l16(const void* g, void* l) {
    __builtin_amdgcn_global_load_lds((const __attribute__((address_space(1))) void*)g,
                                     (__attribute__((address_space(3))) void*)l, 16, 0, 0);
}

// Staging geometry (all gemms): [rows][BK=64] bf16 tiles in LDS, unpadded,
// 16B-unit XOR swizzle (unit ^= row&7) realized by swizzling the global
// SOURCE column (g2l writes lane-linear; reg-staged path writes lane-linear
// to the same layout). Fragment read XORs back -> 0 bank conflicts (R3).

// ---------------------------------------------------------------------------
// proj: q/k/v = xb @ Wb^T + b (all bf16 in), z selects W/bias/output path.
// g2l staging + XOR swizzle; full-line LDS epilogue. (R3-verified, unchanged)
__global__ __launch_bounds__(256)
void gemm_proj(const __bf16* __restrict__ A, const __bf16* __restrict__ Wb,
               __bf16* __restrict__ qkv, const float* __restrict__ bpack)
{
    __shared__ __align__(16) __bf16 smem[128 * 128];   // 32768 B
    __bf16* As = smem;
    __bf16* Bs = smem + 128 * BK;

    const int tid  = threadIdx.x;
    const int w    = tid >> 6;
    const int lane = tid & 63;
    const int quad = lane >> 4;
    const int l16  = lane & 15;
    const int wm   = w & 1;
    const int wn   = w >> 1;

    const int m0 = blockIdx.x * 128;
    const int n0 = blockIdx.y * 128;
    const int z  = blockIdx.z;

    const __bf16* Bb   = Wb + (size_t)z * 131072;
    const float*  bias = bpack + z * 256;

    const int srow = (w << 3) + (lane >> 3);
    const int scol = ((lane & 7) ^ (lane >> 3)) << 3;
    char* ldsA = (char*)As + (size_t)w * 1024;
    char* ldsB = (char*)Bs + (size_t)w * 1024;

    const __bf16* Ag = A  + (size_t)(m0 + srow) * 256 + scol;
    const __bf16* Bg = Bb + (size_t)(n0 + srow) * 256 + scol;

    f32x4 acc[4][4] = {};

    for (int k0 = 0; k0 < 256; k0 += BK) {
        __syncthreads();
        #pragma unroll
        for (int c = 0; c < 4; c++)
            g2l16(Ag + (size_t)(c * 32) * 256 + k0, ldsA + c * 4096);
        #pragma unroll
        for (int c = 0; c < 4; c++)
            g2l16(Bg + (size_t)(c * 32) * 256 + k0, ldsB + c * 4096);
        __syncthreads();

        #pragma unroll
        for (int kk = 0; kk < BK; kk += 32) {
            const int ub = kk >> 3;
            bf16x8 a[4], b[4];
            #pragma unroll
            for (int mt = 0; mt < 4; mt++) {
                const int row = wm * 64 + mt * 16 + l16;
                const int cp  = ((quad + ub) ^ (row & 7)) << 3;
                a[mt] = *(const bf16x8*)&As[row * BK + cp];
            }
            #pragma unroll
            for (int nt = 0; nt < 4; nt++) {
                const int row = wn * 64 + nt * 16 + l16;
                const int cp  = ((quad + ub) ^ (row & 7)) << 3;
                b[nt] = *(const bf16x8*)&Bs[row * BK + cp];
            }
            #pragma unroll
            for (int mt = 0; mt < 4; mt++)
                #pragma unroll
                for (int nt = 0; nt < 4; nt++)
                    acc[mt][nt] = __builtin_amdgcn_mfma_f32_16x16x32_bf16(
                        a[mt], b[nt], acc[mt][nt], 0, 0, 0);
        }
    }

    __syncthreads();
    if (z < 2) {
        #pragma unroll
        for (int mt = 0; mt < 4; mt++) {
            const int rl = wm * 64 + mt * 16 + quad * 4;
            #pragma unroll
            for (int nt = 0; nt < 4; nt++) {
                const int cl = wn * 64 + nt * 16 + l16;
                const float bn = bias[n0 + cl];
                #pragma unroll
                for (int r = 0; r < 4; r++) {
                    const int row = rl + r;
                    smem[row * 128 + ((((cl >> 3) ^ (row & 7)) << 3) | (cl & 7))] =
                        (__bf16)(acc[mt][nt][r] + bn);
                }
            }
        }
        __syncthreads();
        __bf16* C = qkv + (size_t)z * 8388608;
        #pragma unroll
        for (int i = 0; i < 8; i++) {
            const int c   = tid + i * 256;
            const int row = c >> 4, u = c & 15;
            *(bf16x8*)&C[(size_t)(m0 + row) * 256 + n0 + u * 8] =
                *(const bf16x8*)&smem[row * 128 + ((u ^ (row & 7)) << 3)];
        }
    } else {
        #pragma unroll
        for (int mt = 0; mt < 4; mt++) {
            const int ml = wm * 64 + mt * 16 + quad * 4;
            #pragma unroll
            for (int nt = 0; nt < 4; nt++) {
                const int dl = wn * 64 + nt * 16 + l16;
                const float bn = bias[n0 + dl];
                bf16x4 pk;
                #pragma unroll
                for (int r = 0; r < 4; r++) pk[r] = (__bf16)(acc[mt][nt][r] + bn);
                *(bf16x4*)&smem[dl * 128 + ((((ml >> 3) ^ (dl & 7)) << 3) | (ml & 7))] = pk;
            }
        }
        __syncthreads();
        __bf16* C = qkv + 2 * 8388608;
        const int bidx = m0 >> 10, mbase = m0 & 1023;
        #pragma unroll
        for (int i = 0; i < 8; i++) {
            const int c  = tid + i * 256;
            const int dl = c >> 4, u = c & 15;
            *(bf16x8*)&C[(size_t)bidx * 262144 + (size_t)(n0 + dl) * 1024 + mbase + u * 8] =
                *(const bf16x8*)&smem[dl * 128 + ((u ^ (dl & 7)) << 3)];
        }
    }
}

// ---------------------------------------------------------------------------
// logits: E[b] = exp(q[b] @ k[b]^T). R3-verified form (g2l staging, 2-barrier,
// full-line LDS epilogue). R5's direct-fragment variant reverted (strided
// 16B/lane reads collapsed BW). XCD-sequential flat grid.
__global__ __launch_bounds__(256)
void gemm_logits(const __bf16* __restrict__ Q, const __bf16* __restrict__ Km,
                 __bf16* __restrict__ E)
{
    __shared__ __align__(16) __bf16 smem[128 * 128];   // 32768 B
    __bf16* As = smem;
    __bf16* Bs = smem + 128 * BK;

    const int tid  = threadIdx.x;
    const int w    = tid >> 6;
    const int lane = tid & 63;
    const int quad = lane >> 4;
    const int l16  = lane & 15;
    const int wm   = w & 1;
    const int wn   = w >> 1;

    const int id = blockIdx.x;
    const int x  = id & 7, s = id >> 3;
    const int z  = x + ((s >> 6) << 3);
    const int t_ = s & 63;
    const int m0 = (t_ & 7) * 128;
    const int n0 = (t_ >> 3) * 128;

    const __bf16* Ab = Q  + (size_t)z * 262144;
    const __bf16* Bb = Km + (size_t)z * 262144;

    const int srow = (w << 3) + (lane >> 3);
    const int scol = ((lane & 7) ^ (lane >> 3)) << 3;
    char* ldsA = (char*)As + (size_t)w * 1024;
    char* ldsB = (char*)Bs + (size_t)w * 1024;

    const __bf16* Ag = Ab + (size_t)(m0 + srow) * 256 + scol;
    const __bf16* Bg = Bb + (size_t)(n0 + srow) * 256 + scol;

    f32x4 acc[4][4] = {};

    for (int k0 = 0; k0 < 256; k0 += BK) {
        __syncthreads();
        #pragma unroll
        for (int c = 0; c < 4; c++)
            g2l16(Ag + (size_t)(c * 32) * 256 + k0, ldsA + c * 4096);
        #pragma unroll
        for (int c = 0; c < 4; c++)
            g2l16(Bg + (size_t)(c * 32) * 256 + k0, ldsB + c * 4096);
        __syncthreads();

        #pragma unroll
        for (int kk = 0; kk < BK; kk += 32) {
            const int ub = kk >> 3;
            bf16x8 a[4], b[4];
            #pragma unroll
            for (int mt = 0; mt < 4; mt++) {
                const int row = wm * 64 + mt * 16 + l16;
                const int cp  = ((quad + ub) ^ (row & 7)) << 3;
                a[mt] = *(const bf16x8*)&As[row * BK + cp];
            }
            #pragma unroll
            for (int nt = 0; nt < 4; nt++) {
                const int row = wn * 64 + nt * 16 + l16;
                const int cp  = ((quad + ub) ^ (row & 7)) << 3;
                b[nt] = *(const bf16x8*)&Bs[row * BK + cp];
            }
            #pragma unroll
            for (int mt = 0; mt < 4; mt++)
                #pragma unroll
                for (int nt = 0; nt < 4; nt++)
                    acc[mt][nt] = __builtin_amdgcn_mfma_f32_16x16x32_bf16(
                        a[mt], b[nt], acc[mt][nt], 0, 0, 0);
        }
    }

    __syncthreads();
    #pragma unroll
    for (int mt = 0; mt < 4; mt++) {
        const int rl = wm * 64 + mt * 16 + quad * 4;
        #pragma unroll
        for (int nt = 0; nt < 4; nt++) {
            const int cl = wn * 64 + nt * 16 + l16;
            #pragma unroll
            for (int r = 0; r < 4; r++) {
                const int row = rl + r;
                smem[row * 128 + ((((cl >> 3) ^ (row & 7)) << 3) | (cl & 7))] =
                    (__bf16)__expf(acc[mt][nt][r]);
            }
        }
    }
    __syncthreads();
    __bf16* C = E + (size_t)z * 1048576;
    #pragma unroll
    for (int i = 0; i < 8; i++) {
        const int c   = tid + i * 256;
        const int row = c >> 4, u = c & 15;
        *(bf16x8*)&C[(size_t)(m0 + row) * 1024 + n0 + u * 8] =
            *(const bf16x8*)&smem[row * 128 + ((u ^ (row & 7)) << 3)];
    }
}

// ---------------------------------------------------------------------------
// sum_rcp: rcpS[n,m] = 1 / sum_b E[b,n,m], bf16 out (2 MB). Read-only over E.
__global__ __launch_bounds__(256)
void sum_rcp(const __bf16* __restrict__ E, __bf16* __restrict__ rcpS)
{
    const size_t p = (size_t)blockIdx.x * 256 + threadIdx.x;
    const bf16x8* E8 = (const bf16x8*)E;
    float s[8] = {0.f, 0.f, 0.f, 0.f, 0.f, 0.f, 0.f, 0.f};
    #pragma unroll
    for (int b = 0; b < 32; b++) {
        const bf16x8 e = E8[(size_t)b * 131072 + p];
        #pragma unroll
        for (int j = 0; j < 8; j++) s[j] += (float)e[j];
    }
    bf16x8 o;
    #pragma unroll
    for (int j = 0; j < 8; j++) o[j] = (__bf16)__builtin_amdgcn_rcpf(s[j]);
    ((bf16x8*)rcpS)[p] = o;
}

// ---------------------------------------------------------------------------
// pv: out[z] = (E[z] .* rcpS) @ vT[z]^T, normalization fused into A-staging.
// R6: 64x64 tiles. pv is latency-bound (R3: 1.7TB/s on 82MB, MfmaUtil 13%,
// occ 37% -- GRID-limited at 1024 blocks = 4/CU). 64x64 -> grid 2048
// (8 blocks/CU), LDS 16KB (cap 10/CU), 4 waves/block -> 32 waves/CU = full
// occupancy of INDEPENDENT waves (TLP, the only mechanism that has worked
// on this shape; R4 intra-block dbuf and R5 zero-LDS both regressed).
// E/vT re-reads (4x/16x logical) are XCD-L2-hot (2MB/0.5MB per batch).
__global__ __launch_bounds__(256)
void gemm_pv(const __bf16* __restrict__ E, const __bf16* __restrict__ rcpS,
             const __bf16* __restrict__ vT, float* __restrict__ out)
{
    __shared__ __align__(16) __bf16 As[64 * BK];   // 8 KB
    __shared__ __align__(16) __bf16 Bs[64 * BK];   // 8 KB

    const int tid  = threadIdx.x;
    const int w    = tid >> 6;
    const int lane = tid & 63;
    const int quad = lane >> 4;
    const int l16  = lane & 15;
    const int wm   = w & 1;        // 32-row half
    const int wn   = w >> 1;       // 32-col half

    const int id = blockIdx.x;
    const int x  = id & 7, s = id >> 3;        // s: 0..255
    const int z  = x + ((s >> 6) << 3);        // 4 batches per XCD, sequential
    const int t_ = s & 63;
    const int m0 = (t_ & 15) * 64;             // 16 n-row tiles
    const int n0 = (t_ >> 4) * 64;             // 4 d-col tiles

    const __bf16* Eb = E  + (size_t)z * 1048576;
    const __bf16* Vb = vT + (size_t)z * 262144;
    float*        Ob = out + (size_t)z * 262144;

    const int srow = (w << 3) + (lane >> 3);   // 0..31
    const int scol = ((lane & 7) ^ (lane >> 3)) << 3;

    const __bf16* Ag = Eb   + (size_t)(m0 + srow) * 1024 + scol;
    const __bf16* Rg = rcpS + (size_t)(m0 + srow) * 1024 + scol;
    const __bf16* Bg = Vb   + (size_t)(n0 + srow) * 1024 + scol;

    char* ldsAw = (char*)As + w * 1024 + lane * 16;   // reg-staged A (linear)
    char* ldsB  = (char*)Bs + w * 1024;               // g2l B dest

    f32x4 acc[2][2] = {};

    for (int k0 = 0; k0 < 1024; k0 += BK) {
        __syncthreads();
        #pragma unroll
        for (int c = 0; c < 2; c++) {
            const bf16x8 e  = *(const bf16x8*)(Ag + (size_t)(c * 32) * 1024 + k0);
            const bf16x8 rs = *(const bf16x8*)(Rg + (size_t)(c * 32) * 1024 + k0);
            bf16x8 o;
            #pragma unroll
            for (int j = 0; j < 8; j++) o[j] = (__bf16)((float)e[j] * (float)rs[j]);
            *(bf16x8*)(ldsAw + c * 4096) = o;
        }
        #pragma unroll
        for (int c = 0; c < 2; c++)
            g2l16(Bg + (size_t)(c * 32) * 1024 + k0, ldsB + c * 4096);
        __syncthreads();

        #pragma unroll
        for (int kk = 0; kk < BK; kk += 32) {
            const int ub = kk >> 3;
            bf16x8 a[2], b[2];
            #pragma unroll
            for (int mt = 0; mt < 2; mt++) {
                const int row = wm * 32 + mt * 16 + l16;
                const int cp  = ((quad + ub) ^ (row & 7)) << 3;
                a[mt] = *(const bf16x8*)&As[row * BK + cp];
            }
            #pragma unroll
            for (int nt = 0; nt < 2; nt++) {
                const int row = wn * 32 + nt * 16 + l16;
                const int cp  = ((quad + ub) ^ (row & 7)) << 3;
                b[nt] = *(const bf16x8*)&Bs[row * BK + cp];
            }
            #pragma unroll
            for (int mt = 0; mt < 2; mt++)
                #pragma unroll
                for (int nt = 0; nt < 2; nt++)
                    acc[mt][nt] = __builtin_amdgcn_mfma_f32_16x16x32_bf16(
                        a[mt], b[nt], acc[mt][nt], 0, 0, 0);
        }
    }

    // fp32 direct stores: 16 lanes x 4B = full 64B lines.
    #pragma unroll
    for (int mt = 0; mt < 2; mt++) {
        const int mb = m0 + wm * 32 + mt * 16 + quad * 4;
        #pragma unroll
        for (int nt = 0; nt < 2; nt++) {
            const int n = n0 + wn * 32 + nt * 16 + l16;
            #pragma unroll
            for (int r = 0; r < 4; r++)
                Ob[(size_t)(mb + r) * 256 + n] = acc[mt][nt][r];
        }
    }
}

// ---------------------------------------------------------------------------
// One launch: x -> bf16, Wq/Wk/Wv -> bf16, pack 3 fp32 biases.
__global__ __launch_bounds__(256)
void cvt_all(const float* __restrict__ x,
             const float* __restrict__ Wq, const float* __restrict__ Wk,
             const float* __restrict__ Wv,
             const float* __restrict__ bq, const float* __restrict__ bk,
             const float* __restrict__ bv,
             __bf16* __restrict__ xb, __bf16* __restrict__ Wqb,
             float* __restrict__ bpack)
{
    const int i = blockIdx.x * 256 + threadIdx.x;
    if (i < 1073152) {
        const float* s; __bf16* d; int off;
        if (i < 1048576)      { s = x;  d = xb;            off = i; }
        else if (i < 1056768) { s = Wq; d = Wqb;           off = i - 1048576; }
        else if (i < 1064960) { s = Wk; d = Wqb + 131072;  off = i - 1056768; }
        else                  { s = Wv; d = Wqb + 262144;  off = i - 1064960; }
        const float4* s4 = (const float4*)s;
        const float4 f0 = s4[off * 2], f1 = s4[off * 2 + 1];
        bf16x8 o;
        o[0] = (__bf16)f0.x; o[1] = (__bf16)f0.y; o[2] = (__bf16)f0.z; o[3] = (__bf16)f0.w;
        o[4] = (__bf16)f1.x; o[5] = (__bf16)f1.y; o[6] = (__bf16)f1.z; o[7] = (__bf16)f1.w;
        ((bf16x8*)d)[off] = o;
    } else if (i < 1073344) {
        const int j = i - 1073152;
        const int sel = j >> 6, jj = j & 63;
        const float* s = sel == 0 ? bq : (sel == 1 ? bk : bv);
        ((float4*)bpack)[j] = ((const float4*)s)[jj];
    }
}

extern "C" void kernel_launch(void* const* d_in, const int* in_sizes, int n_in,
                              void* d_out, int out_size, void* d_ws, size_t ws_size,
                              hipStream_t stream)
{
    const float* x  = (const float*)d_in[0];
    const float* Wq = (const float*)d_in[1];
    const float* bq = (const float*)d_in[2];
    const float* Wk = (const float*)d_in[3];
    const float* bk = (const float*)d_in[4];
    const float* Wv = (const float*)d_in[5];
    const float* bv = (const float*)d_in[6];
    float* out = (float*)d_out;

    // Workspace layout (bytes):
    //   [0,2M)     rcpS bf16 (1024x1024)
    //   [2M,18M)   xb  bf16 (32768x256)
    //   [18M,34M)  q   bf16 \
    //   [34M,50M)  k   bf16  } stride 8388608 elems
    //   [50M,66M)  vT  bf16 (32,256,1024) /
    //   [66M,130M) E   bf16 (32,1024,1024)
    //   [130M,..)  Wqb bf16 (3 x 65536 elems at 131072-elem stride) + bpack
    char* ws = (char*)d_ws;
    __bf16* rcpS = (__bf16*)ws;
    __bf16* xb   = (__bf16*)(ws + (2u  << 20));
    __bf16* qkv  = (__bf16*)(ws + (18u << 20));
    __bf16* E    = (__bf16*)(ws + (66u << 20));
    __bf16* Wqb  = (__bf16*)(ws + (130u << 20));
    float*  bpack = (float*)(ws + (130u << 20) + (1u << 20));

    // 1) converts + bias pack
    cvt_all<<<4194, 256, 0, stream>>>(x, Wq, Wk, Wv, bq, bk, bv, xb, Wqb, bpack);

    // 2) q/k/v projections
    gemm_proj<<<dim3(256, 2, 3), 256, 0, stream>>>(xb, Wqb, qkv, bpack);

    // 3) E[b] = exp(q[b] @ k[b]^T), XCD-sequential flat grid (R3 form)
    gemm_logits<<<2048, 256, 0, stream>>>(qkv, qkv + 8388608, E);

    // 4) rcpS[n,m] = 1/sum_b E[b,n,m]  (read-only pass; no E write-back)
    sum_rcp<<<512, 256, 0, stream>>>(E, rcpS);

    // 5) out[b] = (E[b] .* rcpS) @ vT[b]^T, 64x64 tiles, full occupancy
    gemm_pv<<<2048, 256, 0, stream>>>(E, rcpS, qkv + 2 * 8388608, out);
}